// Round 1
// baseline (111.963 us; speedup 1.0000x reference)
//
#include <hip/hip_runtime.h>
#include <hip/hip_bf16.h>

typedef __attribute__((ext_vector_type(8))) short bf16x8;
typedef __attribute__((ext_vector_type(4))) float f32x4;

#define B_ 64
#define T_ 1024
#define N_ 512

__device__ __forceinline__ void async16(const void* g, void* l) {
  __builtin_amdgcn_global_load_lds(
      (const __attribute__((address_space(1))) unsigned int*)g,
      (__attribute__((address_space(3))) unsigned int*)l, 16, 0, 0);
}

// Kernel 1: transpose fp32 (B,T,N) -> bf16 (B,N,T); accumulate per-column
// sum and sum-of-squares of the bf16-rounded values (consistent with MFMA).
__global__ __launch_bounds__(256) void k_transpose_stats(
    const float* __restrict__ X, __hip_bfloat16* __restrict__ XbT,
    float* __restrict__ colsum, float* __restrict__ colsumsq)
{
  __shared__ __hip_bfloat16 tile[64][66];   // +2 pad: 2-way (free) on both phases
  __shared__ float psum[256], psumsq[256];
  const int b  = blockIdx.z;
  const int t0 = blockIdx.x * 64;
  const int n0 = blockIdx.y * 64;
  const int tid  = threadIdx.x;
  const int nloc = tid & 63;

  float s = 0.f, sq = 0.f;
  #pragma unroll
  for (int i = 0; i < 16; ++i) {
    int t = (tid >> 6) + i * 4;
    float v = X[((size_t)b * T_ + t0 + t) * N_ + n0 + nloc];   // coalesced
    __hip_bfloat16 bv = __float2bfloat16(v);
    float fv = __bfloat162float(bv);
    s += fv; sq += fv * fv;
    tile[t][nloc] = bv;
  }
  psum[tid] = s; psumsq[tid] = sq;
  __syncthreads();
  if (tid < 64) {
    float ts = psum[tid] + psum[tid + 64] + psum[tid + 128] + psum[tid + 192];
    float tq = psumsq[tid] + psumsq[tid + 64] + psumsq[tid + 128] + psumsq[tid + 192];
    atomicAdd(&colsum[b * N_ + n0 + tid], ts);
    atomicAdd(&colsumsq[b * N_ + n0 + tid], tq);
  }
  #pragma unroll
  for (int i = 0; i < 16; ++i) {
    int n = (tid >> 6) + i * 4;
    // coalesced: consecutive lanes write consecutive t
    XbT[((size_t)b * N_ + n0 + n) * T_ + t0 + (tid & 63)] = tile[tid & 63][n];
  }
}

// Kernel 2: a_n = colsum/sqrt(T);  invd_n = rsqrt(sumsq - colsum^2/T)
__global__ __launch_bounds__(256) void k_finalize(
    const float* __restrict__ colsum, const float* __restrict__ colsumsq,
    float* __restrict__ amu, float* __restrict__ invd)
{
  int i = blockIdx.x * 256 + threadIdx.x;
  if (i >= B_ * N_) return;
  float cs = colsum[i], sq = colsumsq[i];
  float gii = sq - cs * cs * (1.f / (float)T_);
  amu[i]  = cs * (1.f / 32.f);               // 1/sqrt(1024)
  invd[i] = rsqrtf(fmaxf(gii, 1e-20f));
}

// Kernel 3: per-batch Gram via MFMA + correlation epilogue.
// C[i][j] = sum_k XbT[i][k]*XbT[j][k]; corr = (C - a_i a_j)*invd_i*invd_j, clip.
__global__ __launch_bounds__(256) void k_gram(
    const __hip_bfloat16* __restrict__ XbT,
    const float* __restrict__ amu, const float* __restrict__ invd,
    float* __restrict__ out)
{
  __shared__ __align__(16) __hip_bfloat16 ldsA[128][32];  // 8 KB
  __shared__ __align__(16) __hip_bfloat16 ldsB[128][32];  // 8 KB
  const int b       = blockIdx.z;
  const int rowBase = blockIdx.y * 128;
  const int colBase = blockIdx.x * 128;
  const int tid  = threadIdx.x;
  const int lane = tid & 63;
  const int wave = tid >> 6;
  const int wr = wave >> 1, wc = wave & 1;   // 2x2 waves, each owns 64x64 out

  const __hip_bfloat16* Xb = XbT + (size_t)b * N_ * T_;

  f32x4 acc[4][4] = {};

  // staging: tile is 128 rows x 32 k of bf16 = 8192 B = 512 x 16B chunks;
  // thread handles chunks tid and tid+256 (wave-contiguous for load_lds).
  const int c0 = tid, c1 = tid + 256;
  const int r0 = c0 >> 2, k0 = (c0 & 3) * 8;
  const int r1 = c1 >> 2, k1 = (c1 & 3) * 8;

  for (int kt = 0; kt < T_ / 32; ++kt) {
    const int kb = kt * 32;
    async16(Xb + (size_t)(rowBase + r0) * T_ + kb + k0, (char*)&ldsA[0][0] + c0 * 16);
    async16(Xb + (size_t)(rowBase + r1) * T_ + kb + k1, (char*)&ldsA[0][0] + c1 * 16);
    async16(Xb + (size_t)(colBase + r0) * T_ + kb + k0, (char*)&ldsB[0][0] + c0 * 16);
    async16(Xb + (size_t)(colBase + r1) * T_ + kb + k1, (char*)&ldsB[0][0] + c1 * 16);
    __syncthreads();   // compiler drains vmcnt before barrier

    bf16x8 af[4], bfv[4];
    const int kg = (lane >> 4) * 8;
    #pragma unroll
    for (int mi = 0; mi < 4; ++mi)
      af[mi] = *(const bf16x8*)&ldsA[wr * 64 + mi * 16 + (lane & 15)][kg];
    #pragma unroll
    for (int ni = 0; ni < 4; ++ni)
      bfv[ni] = *(const bf16x8*)&ldsB[wc * 64 + ni * 16 + (lane & 15)][kg];

    #pragma unroll
    for (int mi = 0; mi < 4; ++mi)
      #pragma unroll
      for (int ni = 0; ni < 4; ++ni)
        acc[mi][ni] = __builtin_amdgcn_mfma_f32_16x16x32_bf16(
            af[mi], bfv[ni], acc[mi][ni], 0, 0, 0);
    __syncthreads();
  }

  // Epilogue: C/D map (verified): col = lane&15, row = (lane>>4)*4 + reg
  const int jc = colBase + wc * 64 + (lane & 15);
  const int rb = rowBase + wr * 64 + (lane >> 4) * 4;
  float aj[4], dj[4];
  #pragma unroll
  for (int ni = 0; ni < 4; ++ni) {
    aj[ni] = amu[b * N_ + jc + ni * 16];
    dj[ni] = invd[b * N_ + jc + ni * 16];
  }
  #pragma unroll
  for (int mi = 0; mi < 4; ++mi) {
    #pragma unroll
    for (int r = 0; r < 4; ++r) {
      int i = rb + mi * 16 + r;
      float ai = amu[b * N_ + i], di = invd[b * N_ + i];
      float* orow = out + ((size_t)b * N_ + i) * N_;
      #pragma unroll
      for (int ni = 0; ni < 4; ++ni) {
        float g = acc[mi][ni][r] - ai * aj[ni];
        float v = g * di * dj[ni];
        v = fminf(fmaxf(v, -1.f), 1.f);
        orow[jc + ni * 16] = v;
      }
    }
  }
}

extern "C" void kernel_launch(void* const* d_in, const int* in_sizes, int n_in,
                              void* d_out, int out_size, void* d_ws, size_t ws_size,
                              hipStream_t stream) {
  const float* X = (const float*)d_in[0];
  // bn_weight / bn_bias are mathematically irrelevant to the correlation output.
  float* out = (float*)d_out;

  char* ws = (char*)d_ws;
  __hip_bfloat16* XbT = (__hip_bfloat16*)ws;            // 64 MiB
  size_t off = (size_t)B_ * N_ * T_ * sizeof(__hip_bfloat16);
  float* colsum   = (float*)(ws + off);                 // 128 KiB
  float* colsumsq = colsum + B_ * N_;                   // 128 KiB
  float* amu      = colsumsq + B_ * N_;                 // 128 KiB
  float* invd     = amu + B_ * N_;                      // 128 KiB

  hipMemsetAsync(colsum, 0, 2 * B_ * N_ * sizeof(float), stream);
  k_transpose_stats<<<dim3(T_ / 64, N_ / 64, B_), 256, 0, stream>>>(X, XbT, colsum, colsumsq);
  k_finalize<<<dim3((B_ * N_ + 255) / 256), 256, 0, stream>>>(colsum, colsumsq, amu, invd);
  k_gram<<<dim3(N_ / 128, N_ / 128, B_), 256, 0, stream>>>(XbT, amu, invd, out);
}

// Round 2
// 70.067 us; speedup vs baseline: 1.5979x; 1.5979x over previous
//
#include <hip/hip_runtime.h>

typedef __attribute__((ext_vector_type(8))) short bf16x8;
typedef __attribute__((ext_vector_type(4))) short s16x4;
typedef __attribute__((ext_vector_type(4))) float f32x4;

#define B_ 64
#define T_ 1024
#define N_ 512

__device__ __forceinline__ void async16(const void* g, void* l) {
  __builtin_amdgcn_global_load_lds(
      (const __attribute__((address_space(1))) unsigned int*)g,
      (__attribute__((address_space(3))) unsigned int*)l, 16, 0, 0);
}

__device__ __forceinline__ short f2bf(float f) {
  unsigned u = __builtin_bit_cast(unsigned, f);
  u += 0x7fffu + ((u >> 16) & 1u);          // RNE to bf16
  return (short)(u >> 16);
}
__device__ __forceinline__ float bf2f(short s) {
  return __builtin_bit_cast(float, ((unsigned)(unsigned short)s) << 16);
}

// K1: per (n-strip of 64, batch): transpose fp32 (T,N) -> bf16 (N,T), and
// compute full per-column sum / sum-of-squares of the bf16-rounded values
// (consistent with the MFMA Gram). No atomics, no memset, no finalize kernel.
__global__ __launch_bounds__(256, 4) void k_prep(
    const float* __restrict__ X, short* __restrict__ XbT,
    float* __restrict__ amu, float* __restrict__ invd)
{
  __shared__ __align__(16) short tile[64][68];   // 68: 8B-aligned rows, bank-skewed
  const int b   = blockIdx.y;
  const int n0  = blockIdx.x * 64;
  const int tid = threadIdx.x;
  const int nch = tid & 15;    // 16B column chunk (4 floats)
  const int rg  = tid >> 4;    // 0..15

  float s[4] = {0.f,0.f,0.f,0.f}, q[4] = {0.f,0.f,0.f,0.f};

  for (int tt = 0; tt < 16; ++tt) {
    const int t0 = tt * 64;
    #pragma unroll
    for (int i = 0; i < 4; ++i) {
      const int tr = rg + i * 16;
      const float4 v = *(const float4*)&X[((size_t)b*T_ + t0 + tr)*N_ + n0 + nch*4];
      short bb[4];
      bb[0] = f2bf(v.x); bb[1] = f2bf(v.y); bb[2] = f2bf(v.z); bb[3] = f2bf(v.w);
      #pragma unroll
      for (int c = 0; c < 4; ++c) { float f = bf2f(bb[c]); s[c] += f; q[c] += f*f; }
      s16x4 pk = { bb[0], bb[1], bb[2], bb[3] };
      *(s16x4*)&tile[tr][nch*4] = pk;
    }
    __syncthreads();
    #pragma unroll
    for (int i = 0; i < 4; ++i) {
      const int n = rg + i * 16;
      s16x4 o = { tile[nch*4+0][n], tile[nch*4+1][n],
                  tile[nch*4+2][n], tile[nch*4+3][n] };
      *(s16x4*)&XbT[((size_t)b*N_ + n0 + n)*T_ + t0 + nch*4] = o;
    }
    __syncthreads();
  }

  // block-reduce the 16 row-group partials per column
  float* fb = (float*)&tile[0][0];               // 8704 B >= 8192 B needed
  #pragma unroll
  for (int c = 0; c < 4; ++c) { fb[tid*8 + c] = s[c]; fb[tid*8 + 4 + c] = q[c]; }
  __syncthreads();
  if (tid < 64) {
    const int qc = tid >> 2, c = tid & 3;
    float cs = 0.f, sq = 0.f;
    #pragma unroll
    for (int g = 0; g < 16; ++g) {
      cs += fb[(g*16 + qc)*8 + c];
      sq += fb[(g*16 + qc)*8 + 4 + c];
    }
    const int n = n0 + qc*4 + c;
    amu[b*N_ + n]  = cs * (1.f/32.f);                               // cs/sqrt(T)
    invd[b*N_ + n] = rsqrtf(fmaxf(sq - cs*cs*(1.f/1024.f), 1e-20f)); // rsqrt(Gii)
  }
}

// K2: per-batch symmetric Gram, upper-triangular 128x128 tiles only.
// corr[i][j] = (S_ij - a_i a_j) * invd_i * invd_j, clipped; mirror tile
// written with float4 stores. Double-buffered LDS, 1 barrier per K-step,
// XOR-swizzled staging (swizzle applied to global SOURCE, linear LDS dest).
__global__ __launch_bounds__(256, 2) void k_gram(
    const short* __restrict__ XbT, const float* __restrict__ amu,
    const float* __restrict__ invd, float* __restrict__ out)
{
  __shared__ __align__(16) short ldsA[2][128][32];   // 16 KB
  __shared__ __align__(16) short ldsB[2][128][32];   // 16 KB

  // XCD-aware swizzle: 640 blocks = 8 XCDs x 80; each XCD gets 8 whole batches.
  const int bid = (blockIdx.x & 7) * 80 + (blockIdx.x >> 3);
  const int b = bid / 10;
  const int t = bid - b * 10;
  const int ip = (t >= 4) + (t >= 7) + (t >= 9);          // upper-tri row panel
  const int jp = ip + t - ((ip * (9 - ip)) >> 1);         // col panel
  const int rowBase = ip * 128, colBase = jp * 128;
  const bool diag = (ip == jp);

  const int tid = threadIdx.x, lane = tid & 63, wave = tid >> 6;
  const int wr = wave >> 1, wc = wave & 1;                // 2x2 waves, 64x64 each
  const short* Xb = XbT + (size_t)b * N_ * T_;

  // staging: linear LDS chunk q = tid (+256); row r = q>>2, lds chunk cl = q&3;
  // global k-chunk feeding it: cg = cl ^ ((r>>1)&3)  (both-sides involution)
  const int r0 = tid >> 2, cl = tid & 3;
  const int cg = cl ^ ((r0 >> 1) & 3);                    // same for r0+64 (32%4==0)
  const size_t ga0 = (size_t)(rowBase + r0)      * T_ + cg * 8;
  const size_t ga1 = (size_t)(rowBase + r0 + 64) * T_ + cg * 8;
  const size_t gb0 = (size_t)(colBase + r0)      * T_ + cg * 8;
  const size_t gb1 = (size_t)(colBase + r0 + 64) * T_ + cg * 8;

  const int fr = lane & 15, kc = lane >> 4;
  const int swz = (kc ^ ((fr >> 1) & 3)) * 8;             // fragment read swizzle

  f32x4 acc[4][4] = {};

  #define STAGE(bufi, kb)                                                    \
    do {                                                                     \
      char* la_ = (char*)&ldsA[bufi][0][0];                                  \
      async16(Xb + ga0 + (kb), la_ + tid * 16);                              \
      async16(Xb + ga1 + (kb), la_ + (tid + 256) * 16);                      \
      if (!diag) {                                                           \
        char* lb_ = (char*)&ldsB[bufi][0][0];                                \
        async16(Xb + gb0 + (kb), lb_ + tid * 16);                            \
        async16(Xb + gb1 + (kb), lb_ + (tid + 256) * 16);                    \
      }                                                                      \
    } while (0)

  STAGE(0, 0);
  __syncthreads();
  int cur = 0;
  #pragma unroll 1
  for (int kt = 0; kt < 32; ++kt) {
    if (kt < 31) STAGE(cur ^ 1, (kt + 1) * 32);           // prefetch next tile
    const short (*A)[32]  = ldsA[cur];
    const short (*Bm)[32] = diag ? ldsA[cur] : ldsB[cur];
    bf16x8 af[4], bfv[4];
    #pragma unroll
    for (int mi = 0; mi < 4; ++mi)
      af[mi] = *(const bf16x8*)&A[wr*64 + mi*16 + fr][swz];
    #pragma unroll
    for (int ni = 0; ni < 4; ++ni)
      bfv[ni] = *(const bf16x8*)&Bm[wc*64 + ni*16 + fr][swz];
    #pragma unroll
    for (int mi = 0; mi < 4; ++mi)
      #pragma unroll
      for (int ni = 0; ni < 4; ++ni)
        acc[mi][ni] = __builtin_amdgcn_mfma_f32_16x16x32_bf16(
            af[mi], bfv[ni], acc[mi][ni], 0, 0, 0);
    __syncthreads();                                      // drains vmcnt+lgkm
    cur ^= 1;
  }

  // Epilogue. C/D map: col = lane&15, row = (lane>>4)*4 + reg.
  const int jc = colBase + wc * 64 + fr;
  float aj[4], dj[4];
  #pragma unroll
  for (int ni = 0; ni < 4; ++ni) {
    aj[ni] = amu[b*N_ + jc + ni*16];
    dj[ni] = invd[b*N_ + jc + ni*16];
  }
  #pragma unroll
  for (int mi = 0; mi < 4; ++mi) {
    const int ibase = rowBase + wr*64 + mi*16 + kc*4;
    float ai[4], di[4];
    #pragma unroll
    for (int r = 0; r < 4; ++r) {
      ai[r] = amu[b*N_ + ibase + r];
      di[r] = invd[b*N_ + ibase + r];
    }
    #pragma unroll
    for (int ni = 0; ni < 4; ++ni) {
      f32x4 g;
      #pragma unroll
      for (int r = 0; r < 4; ++r) {
        float v = (acc[mi][ni][r] - ai[r]*aj[ni]) * (di[r]*dj[ni]);
        g[r] = fminf(fmaxf(v, -1.f), 1.f);
      }
      const int J = jc + ni*16;
      #pragma unroll
      for (int r = 0; r < 4; ++r)
        out[((size_t)b*N_ + ibase + r)*N_ + J] = g[r];    // tile (ip,jp)
      if (!diag)
        *(f32x4*)&out[((size_t)b*N_ + J)*N_ + ibase] = g; // mirror tile (jp,ip)
    }
  }
}

extern "C" void kernel_launch(void* const* d_in, const int* in_sizes, int n_in,
                              void* d_out, int out_size, void* d_ws, size_t ws_size,
                              hipStream_t stream) {
  const float* X = (const float*)d_in[0];
  // bn_weight / bn_bias provably cancel in the correlation output.
  float* out = (float*)d_out;

  char* ws = (char*)d_ws;
  short* XbT  = (short*)ws;                                  // 64 MiB bf16 (N,T)
  size_t off  = (size_t)B_ * N_ * T_ * sizeof(short);
  float* amu  = (float*)(ws + off);                          // 128 KiB
  float* invd = amu + B_ * N_;                               // 128 KiB

  k_prep<<<dim3(N_/64, B_), 256, 0, stream>>>(X, XbT, amu, invd);
  k_gram<<<dim3(64 * 10), 256, 0, stream>>>(XbT, amu, invd, out);
}